// Round 3
// baseline (469.705 us; speedup 1.0000x reference)
//
#include <hip/hip_runtime.h>

// Problem constants (fixed by the reference)
#define H_DIM   1024
#define G_DIM   128
#define N_DIM   384          // 3*G
#define M_TOTAL 65536        // 32*2048 rows
#define BM      64           // rows per block
#define LDA     72           // LDS A row stride in halfs (64 + 8 pad)
#define ABUF    (BM * LDA)   // one LDS A buffer, in halfs (9216 B)

typedef _Float16 half8  __attribute__((ext_vector_type(8)));
typedef __fp16   fp16x2 __attribute__((ext_vector_type(2)));
typedef float    f32x4  __attribute__((ext_vector_type(4)));

__device__ __forceinline__ float fast_sigmoid(float v) {
    return 1.0f / (1.0f + __expf(-v));
}
__device__ __forceinline__ float fast_tanh(float v) {
    // tanh(v) = 1 - 2/(exp(2v)+1); saturates correctly at +/-inf
    return 1.0f - 2.0f / (__expf(2.0f * v) + 1.0f);
}

__device__ __forceinline__ half8 cvt8(f32x4 a, f32x4 b) {
    fp16x2 p0 = __builtin_amdgcn_cvt_pkrtz(a[0], a[1]);
    fp16x2 p1 = __builtin_amdgcn_cvt_pkrtz(a[2], a[3]);
    fp16x2 p2 = __builtin_amdgcn_cvt_pkrtz(b[0], b[1]);
    fp16x2 p3 = __builtin_amdgcn_cvt_pkrtz(b[2], b[3]);
    half8 h;
    h[0] = (_Float16)p0[0]; h[1] = (_Float16)p0[1];
    h[2] = (_Float16)p1[0]; h[3] = (_Float16)p1[1];
    h[4] = (_Float16)p2[0]; h[5] = (_Float16)p2[1];
    h[6] = (_Float16)p3[0]; h[7] = (_Float16)p3[1];
    return h;
}

// Convert weight_ih (384x1024 fp32 row-major = B^T, K contiguous) into f16
// fragments, fragment-linear: frag index (ct*32 + ktg), 64 lanes x 8 halfs.
// Lane holds B^T[col = ct*16 + (lane&15)][k = ktg*32 + (lane>>4)*8 .. +8].
__global__ __launch_bounds__(256) void prep_w_kernel(const float* __restrict__ w,
                                                     _Float16* __restrict__ wf) {
    int gid  = blockIdx.x * 256 + threadIdx.x;   // 0 .. 49151
    int lane = gid & 63;
    int fid  = gid >> 6;
    int ktg  = fid & 31;
    int ct   = fid >> 5;
    int col  = ct * 16 + (lane & 15);
    int kb   = ktg * 32 + (lane >> 4) * 8;
    const f32x4* src = (const f32x4*)(w + (size_t)col * H_DIM + kb);
    f32x4 v0 = src[0], v1 = src[1];
    half8 h;
    #pragma unroll
    for (int j = 0; j < 4; ++j) { h[j] = (_Float16)v0[j]; h[4 + j] = (_Float16)v1[j]; }
    *(half8*)(wf + (size_t)gid * 8) = h;
}

// Fused: gi = x @ W^T (f16 MFMA, fp32 acc) -> GRU gates -> dot(lin_w) -> out
// Software-pipelined: register prefetch of the next x tile; double-buffered
// LDS A; one barrier per K-step.
__global__ __launch_bounds__(256) void ping_main_kernel(
    const float* __restrict__ x, const _Float16* __restrict__ wf,
    const float* __restrict__ bias_ih, const float* __restrict__ bias_hh,
    const float* __restrict__ lin_w, const float* __restrict__ lin_b,
    float* __restrict__ out)
{
    __shared__ _Float16 shA[2 * ABUF];
    __shared__ float sh_out[BM];

    const int t    = threadIdx.x;       // 0..255
    const int lane = t & 63;
    const int wv   = t >> 6;            // wave 0..3
    const int ln   = lane & 15;
    const int quad = lane >> 4;

    if (t < BM) sh_out[t] = 0.0f;

    const size_t row0 = (size_t)blockIdx.x * BM;

    f32x4 acc[6][4];
    #pragma unroll
    for (int i = 0; i < 6; ++i)
        #pragma unroll
        for (int rt = 0; rt < 4; ++rt)
            acc[i][rt] = (f32x4){0.f, 0.f, 0.f, 0.f};

    // staging mapping: thread -> (row, 16-float k-chunk)
    const int rs = t >> 2;              // 0..63
    const int kg = (t & 3) * 16;        // 0,16,32,48
    const float* xptr = x + (row0 + rs) * (size_t)H_DIM + kg;
    _Float16* sW0 = &shA[rs * LDA + kg];
    _Float16* sW1 = sW0 + ABUF;

    // B fragment pointers, strength-reduced: advance 1024 halfs per K-step
    const _Float16* pb[6];
    #pragma unroll
    for (int i = 0; i < 6; ++i) {
        const int ct = ((i >> 1) * 8) + 2 * wv + (i & 1);
        pb[i] = wf + ((size_t)(ct * 32) * 64 + lane) * 8;
    }

    // prologue: stage tile 0 into buffer 0
    f32x4 q0, q1, q2, q3;
    { const f32x4* s = (const f32x4*)xptr; q0 = s[0]; q1 = s[1]; q2 = s[2]; q3 = s[3]; xptr += 64; }
    *(half8*)sW0       = cvt8(q0, q1);
    *(half8*)(sW0 + 8) = cvt8(q2, q3);
    __syncthreads();

    #pragma unroll
    for (int kb = 0; kb < 16; ++kb) {
        const bool pref = (kb < 15);
        // issue prefetch of next x tile (HBM latency hidden behind MFMAs below)
        if (pref) { const f32x4* s = (const f32x4*)xptr; q0 = s[0]; q1 = s[1]; q2 = s[2]; q3 = s[3]; xptr += 64; }

        const _Float16* aRd = (kb & 1) ? (shA + ABUF) : shA;
        #pragma unroll
        for (int kt = 0; kt < 2; ++kt) {
            half8 b[6];
            #pragma unroll
            for (int i = 0; i < 6; ++i)
                b[i] = *(const half8*)(pb[i] + kt * 512);
            half8 a[4];
            #pragma unroll
            for (int rt = 0; rt < 4; ++rt)
                a[rt] = *(const half8*)(aRd + (rt * 16 + ln) * LDA + kt * 32 + quad * 8);
            #pragma unroll
            for (int i = 0; i < 6; ++i)
                #pragma unroll
                for (int rt = 0; rt < 4; ++rt)
                    acc[i][rt] = __builtin_amdgcn_mfma_f32_16x16x32_f16(a[rt], b[i], acc[i][rt], 0, 0, 0);
        }
        #pragma unroll
        for (int i = 0; i < 6; ++i) pb[i] += 1024;

        // convert prefetched registers into the other LDS buffer
        if (pref) {
            _Float16* w = (kb & 1) ? sW0 : sW1;
            *(half8*)w       = cvt8(q0, q1);
            *(half8*)(w + 8) = cvt8(q2, q3);
        }
        __syncthreads();
    }

    // Epilogue: per lane, columns g = 32*wv + 16*i + ln for i in {0,1};
    // acc[i] = r-part, acc[2+i] = z-part, acc[4+i] = n-part (same g, same lanes).
    float psum[4][4];
    #pragma unroll
    for (int rt = 0; rt < 4; ++rt)
        #pragma unroll
        for (int reg = 0; reg < 4; ++reg)
            psum[rt][reg] = 0.f;

    #pragma unroll
    for (int i = 0; i < 2; ++i) {
        const int g = 32 * wv + 16 * i + ln;
        const float b_ir = bias_ih[g];
        const float b_iz = bias_ih[G_DIM + g];
        const float b_in = bias_ih[2 * G_DIM + g];
        const float b_hr = bias_hh[g];
        const float b_hz = bias_hh[G_DIM + g];
        const float b_hn = bias_hh[2 * G_DIM + g];
        const float lw   = lin_w[g];
        #pragma unroll
        for (int rt = 0; rt < 4; ++rt) {
            #pragma unroll
            for (int reg = 0; reg < 4; ++reg) {
                const float r = fast_sigmoid(acc[i][rt][reg] + b_ir + b_hr);
                const float z = fast_sigmoid(acc[2 + i][rt][reg] + b_iz + b_hz);
                const float n = fast_tanh(acc[4 + i][rt][reg] + b_in + r * b_hn);
                psum[rt][reg] += lw * (1.0f - z) * n;
            }
        }
    }

    // reduce across the 16 lanes of each quad-row first (shuffles), then one
    // LDS atomic per wave per row instead of 16.
    #pragma unroll
    for (int rt = 0; rt < 4; ++rt) {
        #pragma unroll
        for (int reg = 0; reg < 4; ++reg) {
            float v = psum[rt][reg];
            v += __shfl_xor(v, 1);
            v += __shfl_xor(v, 2);
            v += __shfl_xor(v, 4);
            v += __shfl_xor(v, 8);
            if (ln == 0) atomicAdd(&sh_out[rt * 16 + quad * 4 + reg], v);
        }
    }

    __syncthreads();
    if (t < BM) out[row0 + t] = sh_out[t] + lin_b[0];
}

extern "C" void kernel_launch(void* const* d_in, const int* in_sizes, int n_in,
                              void* d_out, int out_size, void* d_ws, size_t ws_size,
                              hipStream_t stream) {
    const float* x      = (const float*)d_in[0];
    const float* w_ih   = (const float*)d_in[1];
    // d_in[2] = weight_hh: unused (hidden state is always zero in the reference)
    const float* b_ih   = (const float*)d_in[3];
    const float* b_hh   = (const float*)d_in[4];
    const float* lin_w  = (const float*)d_in[5];
    const float* lin_b  = (const float*)d_in[6];
    float* out          = (float*)d_out;
    _Float16* wf        = (_Float16*)d_ws;   // 384*1024*2 = 768 KB scratch

    hipLaunchKernelGGL(prep_w_kernel, dim3((N_DIM / 16) * 32 * 64 / 256), dim3(256), 0, stream,
                       w_ih, wf);
    hipLaunchKernelGGL(ping_main_kernel, dim3(M_TOTAL / BM), dim3(256), 0, stream,
                       x, wf, b_ih, b_hh, lin_w, lin_b, out);
}

// Round 4
// 408.060 us; speedup vs baseline: 1.1511x; 1.1511x over previous
//
#include <hip/hip_runtime.h>

// Problem constants (fixed by the reference)
#define H_DIM   1024
#define G_DIM   128
#define N_DIM   384            // 3*G
#define M_TOTAL 65536          // 32*2048 rows
#define BM      64             // rows per block
#define NSTEP   32             // K-steps of BK=32
#define BUF_FLOATS 2048        // one LDS x-buffer: 64 rows x 32 fp32 = 8 KB

typedef _Float16 half8  __attribute__((ext_vector_type(8)));
typedef __fp16   fp16x2 __attribute__((ext_vector_type(2)));
typedef float    f32x4  __attribute__((ext_vector_type(4)));

__device__ __forceinline__ float fast_sigmoid(float v) {
    return 1.0f / (1.0f + __expf(-v));
}
__device__ __forceinline__ float fast_tanh(float v) {
    return 1.0f - 2.0f / (__expf(2.0f * v) + 1.0f);
}

__device__ __forceinline__ half8 cvt8(f32x4 a, f32x4 b) {
    fp16x2 p0 = __builtin_amdgcn_cvt_pkrtz(a[0], a[1]);
    fp16x2 p1 = __builtin_amdgcn_cvt_pkrtz(a[2], a[3]);
    fp16x2 p2 = __builtin_amdgcn_cvt_pkrtz(b[0], b[1]);
    fp16x2 p3 = __builtin_amdgcn_cvt_pkrtz(b[2], b[3]);
    half8 h;
    h[0] = (_Float16)p0[0]; h[1] = (_Float16)p0[1];
    h[2] = (_Float16)p1[0]; h[3] = (_Float16)p1[1];
    h[4] = (_Float16)p2[0]; h[5] = (_Float16)p2[1];
    h[6] = (_Float16)p3[0]; h[7] = (_Float16)p3[1];
    return h;
}

// weight_ih (384x1024 fp32 row-major = B^T, K contiguous) -> f16 fragments,
// fragment-linear: frag id f = ct*32 + ktg (ktg = 32-wide K group), layout
// wf[f*512 + lane*8]: lane holds B^T[col=ct*16+(lane&15)][k=ktg*32+(lane>>4)*8 ..+8]
__global__ __launch_bounds__(256) void prep_w_kernel(const float* __restrict__ w,
                                                     _Float16* __restrict__ wf) {
    int gid  = blockIdx.x * 256 + threadIdx.x;   // 0 .. 49151
    int lane = gid & 63;
    int fid  = gid >> 6;
    int ktg  = fid & 31;
    int ct   = fid >> 5;
    int col  = ct * 16 + (lane & 15);
    int kb   = ktg * 32 + (lane >> 4) * 8;
    const f32x4* src = (const f32x4*)(w + (size_t)col * H_DIM + kb);
    f32x4 v0 = src[0], v1 = src[1];
    half8 h;
    #pragma unroll
    for (int j = 0; j < 4; ++j) { h[j] = (_Float16)v0[j]; h[4 + j] = (_Float16)v1[j]; }
    *(half8*)(wf + (size_t)gid * 8) = h;
}

// ---- raw barrier / waitcnt (NO vmcnt(0) drain like __syncthreads) ----
#define FENCE() asm volatile("" ::: "memory")
// gfx9 waitcnt imm: vmcnt[3:0], expcnt[6:4]=7 (nowait), lgkmcnt[11:8]=15 (nowait)
#define WAITV(N) { FENCE(); __builtin_amdgcn_s_waitcnt(0x0F70 | (N)); FENCE(); }
#define BARR()   { FENCE(); __builtin_amdgcn_s_barrier(); FENCE(); }

__global__ __launch_bounds__(512, 4) void ping_main_kernel(
    const float* __restrict__ x, const _Float16* __restrict__ wf,
    const float* __restrict__ bias_ih, const float* __restrict__ bias_hh,
    const float* __restrict__ lin_w, const float* __restrict__ lin_b,
    float* __restrict__ out)
{
    __shared__ float shX[4 * BUF_FLOATS];   // 32 KB: 4 buffers of 64x32 fp32
    __shared__ float sh_out[BM];

    const int t    = threadIdx.x;       // 0..511
    const int lane = t & 63;
    const int wv   = t >> 6;            // wave 0..7
    const int ln   = lane & 15;
    const int quad = lane >> 4;

    if (t < BM) sh_out[t] = 0.0f;

    const size_t row0 = (size_t)blockIdx.x * BM;

    // --- DMA source mapping (1 global_load_lds of 16B per thread per step) ---
    // wave wv stages rows 8wv..8wv+7; lane l -> row 8wv + l/8, LDS chunk l%8.
    // XOR pair-swizzle on SOURCE chunk so LDS rows aren't bank-aliased:
    // LDS (r, c) holds global chunk c ^ (2*(r&3)).
    const int drow = wv * 8 + (lane >> 3);                 // 0..63
    const int cg   = (lane & 7) ^ (2 * ((lane >> 3) & 3)); // source chunk
    const float* xsrc = x + (row0 + drow) * (size_t)H_DIM + cg * 4;
    float* ldsSeg = &shX[wv * 256];     // wave-uniform base within buffer 0

#define DMA_ISSUE(K) \
    __builtin_amdgcn_global_load_lds( \
        (const __attribute__((address_space(1))) void*)(xsrc + (size_t)(K) * 32), \
        (__attribute__((address_space(3))) void*)(ldsSeg + ((K) & 3) * BUF_FLOATS), \
        16, 0, 0)

    // --- A fragment read addresses (even chunk of the pair; odd at +16B) ---
    const char* aAddr[4];
    #pragma unroll
    for (int rt = 0; rt < 4; ++rt) {
        int r  = rt * 16 + ln;
        int ce = (2 * quad) ^ (2 * (ln & 3));   // swizzled even chunk
        aAddr[rt] = (const char*)&shX[0] + r * 128 + ce * 16;
    }

    // --- B fragment pointers: wave wv owns ct in {wv, wv+8, wv+16} so the
    // (r,z,n) triple for gate column g = 16*wv + ln stays lane-local. ---
    const _Float16* pb[3];
    #pragma unroll
    for (int i = 0; i < 3; ++i)
        pb[i] = wf + (size_t)((wv + 8 * i) * 32) * 512 + lane * 8;

    f32x4 acc[3][4];
    #pragma unroll
    for (int i = 0; i < 3; ++i)
        #pragma unroll
        for (int rt = 0; rt < 4; ++rt)
            acc[i][rt] = (f32x4){0.f, 0.f, 0.f, 0.f};

    // prologue: 3 steps in flight
    DMA_ISSUE(0); DMA_ISSUE(1); DMA_ISSUE(2);

#define ITER_BODY(KB, BUFI, WAITN, DO_ISSUE) { \
    WAITV(WAITN); \
    BARR(); \
    if (DO_ISSUE) { DMA_ISSUE((KB) + 3); } \
    half8 bfr[3]; \
    _Pragma("unroll") \
    for (int i = 0; i < 3; ++i) \
        bfr[i] = *(const half8*)(pb[i] + (size_t)(KB) * 512); \
    _Pragma("unroll") \
    for (int rt = 0; rt < 4; ++rt) { \
        f32x4 ve = *(const f32x4*)(aAddr[rt] + (BUFI) * 8192); \
        f32x4 vo = *(const f32x4*)(aAddr[rt] + (BUFI) * 8192 + 16); \
        half8 afr = cvt8(ve, vo); \
        _Pragma("unroll") \
        for (int i = 0; i < 3; ++i) \
            acc[i][rt] = __builtin_amdgcn_mfma_f32_16x16x32_f16(afr, bfr[i], acc[i][rt], 0, 0, 0); \
    } }

    for (int kb = 0; kb < 28; kb += 4) {
        ITER_BODY(kb + 0, 0, 2, true);
        ITER_BODY(kb + 1, 1, 2, true);
        ITER_BODY(kb + 2, 2, 2, true);
        ITER_BODY(kb + 3, 3, 2, true);
    }
    ITER_BODY(28, 0, 2, true);    // issues step 31 (last)
    ITER_BODY(29, 1, 2, false);
    ITER_BODY(30, 2, 1, false);
    ITER_BODY(31, 3, 0, false);

    // --- Epilogue: gate column g = 16*wv + ln; acc[0]=r, acc[1]=z, acc[2]=n ---
    const int g = 16 * wv + ln;
    const float b_ir = bias_ih[g];
    const float b_iz = bias_ih[G_DIM + g];
    const float b_in = bias_ih[2 * G_DIM + g];
    const float b_hr = bias_hh[g];
    const float b_hz = bias_hh[G_DIM + g];
    const float b_hn = bias_hh[2 * G_DIM + g];
    const float lw   = lin_w[g];

    #pragma unroll
    for (int rt = 0; rt < 4; ++rt) {
        #pragma unroll
        for (int reg = 0; reg < 4; ++reg) {
            const float r = fast_sigmoid(acc[0][rt][reg] + b_ir + b_hr);
            const float z = fast_sigmoid(acc[1][rt][reg] + b_iz + b_hz);
            const float n = fast_tanh(acc[2][rt][reg] + b_in + r * b_hn);
            float v = lw * (1.0f - z) * n;
            // reduce over the 16 gate columns held by this quad-row group
            v += __shfl_xor(v, 1);
            v += __shfl_xor(v, 2);
            v += __shfl_xor(v, 4);
            v += __shfl_xor(v, 8);
            if (ln == 0) atomicAdd(&sh_out[rt * 16 + quad * 4 + reg], v);
        }
    }

    __syncthreads();
    if (t < BM) out[row0 + t] = sh_out[t] + lin_b[0];
}

extern "C" void kernel_launch(void* const* d_in, const int* in_sizes, int n_in,
                              void* d_out, int out_size, void* d_ws, size_t ws_size,
                              hipStream_t stream) {
    const float* x      = (const float*)d_in[0];
    const float* w_ih   = (const float*)d_in[1];
    // d_in[2] = weight_hh: unused (hidden state is always zero in the reference)
    const float* b_ih   = (const float*)d_in[3];
    const float* b_hh   = (const float*)d_in[4];
    const float* lin_w  = (const float*)d_in[5];
    const float* lin_b  = (const float*)d_in[6];
    float* out          = (float*)d_out;
    _Float16* wf        = (_Float16*)d_ws;   // 384*1024*2 = 768 KB scratch

    hipLaunchKernelGGL(prep_w_kernel, dim3((N_DIM / 16) * 32 * 64 / 256), dim3(256), 0, stream,
                       w_ih, wf);
    hipLaunchKernelGGL(ping_main_kernel, dim3(M_TOTAL / BM), dim3(512), 0, stream,
                       x, wf, b_ih, b_hh, lin_w, lin_b, out);
}